// Round 2
// baseline (593.372 us; speedup 1.0000x reference)
//
#include <hip/hip_runtime.h>
#include <hip/hip_bf16.h>

#define LLEN 512
#define SLEN 64
#define EMBD 16
#define EE 48
#define GG 4
#define MMB 3
#define NHH 8
#define KDD 4
#define INDIM 224
#define H1D 200
#define H2D 80
#define CHUNK 128
#define PXE 52   // padded row stride (floats): 208B, 16B-aligned, odd multiple of 4 -> spreads banks

__device__ __forceinline__ float bf2f(unsigned short u) {
    union { unsigned int i; float f; } v; v.i = ((unsigned int)u) << 16; return v.f;
}

template<bool BF16>
__device__ __forceinline__ float ldf(const void* p, int i) {
    if constexpr (BF16) return bf2f(((const unsigned short*)p)[i]);
    else                return ((const float*)p)[i];
}

// ---- dtype detection: even ushort indices of a bf16 tensor are real values
// (|v|<1 for the 0.05-scale table => exponent<127); of an fp32 tensor they are
// low-half mantissa bits (random 16-bit patterns: P(all 128 exps<127) ~ 2^-128).
__global__ void detect_dtype(const unsigned short* __restrict__ tbl, int* __restrict__ flag) {
    int t = threadIdx.x;
    int big = 0;
    for (int i = t; i < 128; i += 64) {
        unsigned short u = tbl[2 * i];
        int ex = (u >> 7) & 0xFF;
        if (ex >= 127) big = 1;
    }
    unsigned long long m = __ballot(big);
    if (t == 0) flag[0] = (m == 0ull) ? 1 : 0;   // 1 => bf16, 0 => fp32
}

template<bool BF16>
__global__ __launch_bounds__(256) void sdim_fwd(
    const int* __restrict__ uid, const int* __restrict__ ut1, const int* __restrict__ ut2,
    const int* __restrict__ ut3, const int* __restrict__ ut4,
    const int* __restrict__ lb_g, const int* __restrict__ lb_s, const int* __restrict__ lb_c,
    const int* __restrict__ lt_g, const int* __restrict__ lt_s, const int* __restrict__ lt_c,
    const int* __restrict__ st_g, const int* __restrict__ st_s, const int* __restrict__ st_c,
    const void* __restrict__ tbl, const void* __restrict__ Hm,
    const void* __restrict__ wq, const void* __restrict__ bq,
    const void* __restrict__ wk, const void* __restrict__ bk,
    const void* __restrict__ wv, const void* __restrict__ bv,
    const void* __restrict__ wo, const void* __restrict__ bo,
    const void* __restrict__ w1, const void* __restrict__ b1,
    const void* __restrict__ g1, const void* __restrict__ be1,
    const void* __restrict__ w2, const void* __restrict__ b2,
    const void* __restrict__ g2, const void* __restrict__ be2,
    const void* __restrict__ w3, const void* __restrict__ b3,
    void* __restrict__ outp, const int* __restrict__ flagp)
{
    // uniform early-exit: only the instantiation matching the detected dtype runs
    if (flagp) { if (flagp[0] != (BF16 ? 1 : 0)) return; }
    else       { if (BF16) return; }   // no workspace: assume fp32 (reference dtype)

    const int b = blockIdx.x;
    const int tid = threadIdx.x;

    __shared__ alignas(16) float sHf[EE * 12];        // H as fp32, [e][g*3+m]
    __shared__ float s_csum[GG][8][EE];               // bucket sums
    __shared__ float s_vc[GG][8];                     // bucket counts (incl. padded)
    __shared__ float s_feat[INDIM];                   // final 224-d feature
    __shared__ float s_q[NHH * KDD];
    __shared__ float s_red[128];
    __shared__ int   s_icode[GG];
    __shared__ int   s_len;
    __shared__ float s_mu, s_rstd;
    __shared__ alignas(16) float s_buf[CHUNK * PXE];  // 6656 floats
    __shared__ int   s_code[CHUNK];

    // ---------------- phase 0: H -> LDS, zero buckets, Xu/Xi embeds -> feat ----------------
    for (int i = tid; i < EE * 12; i += 256) sHf[i] = ldf<BF16>(Hm, i);
    for (int i = tid; i < GG * 8 * EE; i += 256) ((float*)s_csum)[i] = 0.f;
    if (tid < GG * 8) ((float*)s_vc)[tid] = 0.f;
    if (tid < 80) {
        int f = tid >> 4, e = tid & 15;
        int id = (f == 0) ? uid[b] : (f == 1) ? ut1[b] : (f == 2) ? ut2[b] : (f == 3) ? ut3[b] : ut4[b];
        s_feat[tid] = ldf<BF16>(tbl, id * EMBD + e);
    } else if (tid < 128) {
        int t = tid - 80; int f = t >> 4, e = t & 15;
        int id = (f == 0) ? lb_g[b] : (f == 1) ? lb_s[b] : lb_c[b];
        s_feat[80 + t] = ldf<BF16>(tbl, id * EMBD + e);
    }
    __syncthreads();

    // ---------------- phase 0.5: q projection + item LSH projections ----------------
    if (tid < 32) {
        float acc = ldf<BF16>(bq, tid);
        for (int e = 0; e < EE; e++) acc += s_feat[80 + e] * ldf<BF16>(wq, e * 32 + tid);
        s_q[tid] = acc;
    }
    if (tid >= 64 && tid < 64 + GG * MMB) {
        int t = tid - 64;
        float acc = 0.f;
        for (int e = 0; e < EE; e++) acc += s_feat[80 + e] * sHf[e * 12 + t];
        s_red[t] = acc;
    }
    __syncthreads();
    if (tid < GG) {
        int code = 0;
        #pragma unroll
        for (int m = 0; m < MMB; m++) if (s_red[tid * 3 + m] > 0.f) code |= (1 << m);
        s_icode[tid] = code;
    }

    // ---------------- phase 1: long-term, 4 chunks of 128 positions ----------------
    for (int ch = 0; ch < LLEN / CHUNK; ch++) {
        const int base = ch * CHUNK;
        // A: gather chunk embeddings -> s_buf[p*PXE + e]
        for (int f = tid; f < CHUNK * EE; f += 256) {
            int p = f / EE, e = f - p * EE;
            int fe = e >> 4;
            const int* idp = (fe == 0) ? lt_g : (fe == 1) ? lt_s : lt_c;
            int id = idp[b * LLEN + base + p];
            s_buf[p * PXE + e] = ldf<BF16>(tbl, id * EMBD + (e & 15));
        }
        __syncthreads();
        // B: LSH codes (thread = position); H reads are wave-uniform LDS broadcasts
        if (tid < CHUNK) {
            const int p = tid;
            float x[EE];
            const float4* xr = (const float4*)&s_buf[p * PXE];
            #pragma unroll
            for (int k = 0; k < 12; k++) {
                float4 t4 = xr[k];
                x[4 * k] = t4.x; x[4 * k + 1] = t4.y; x[4 * k + 2] = t4.z; x[4 * k + 3] = t4.w;
            }
            float acc[12];
            #pragma unroll
            for (int j = 0; j < 12; j++) acc[j] = 0.f;
            #pragma unroll 4
            for (int e = 0; e < EE; e++) {
                const float4* hp = (const float4*)&sHf[e * 12];
                float4 h0 = hp[0], h1 = hp[1], h2 = hp[2];
                float xe = x[e];
                acc[0] += xe * h0.x; acc[1] += xe * h0.y; acc[2]  += xe * h0.z; acc[3]  += xe * h0.w;
                acc[4] += xe * h1.x; acc[5] += xe * h1.y; acc[6]  += xe * h1.z; acc[7]  += xe * h1.w;
                acc[8] += xe * h2.x; acc[9] += xe * h2.y; acc[10] += xe * h2.z; acc[11] += xe * h2.w;
            }
            int packed = 0;
            #pragma unroll
            for (int g = 0; g < GG; g++) {
                int code = 0;
                #pragma unroll
                for (int m = 0; m < MMB; m++) if (acc[g * 3 + m] > 0.f) code |= (1 << m);
                packed |= code << (3 * g);
                atomicAdd(&s_vc[g][code], 1.0f);   // counts include padded positions (ref semantics)
            }
            int valid = (lt_g[b * LLEN + base + p] != 0) ? 1 : 0;
            s_code[p] = packed | (valid << 15);
        }
        __syncthreads();
        // C: masked scatter-add, lane = e (wave-uniform position loop)
        {
            const int w = tid >> 6, lane = tid & 63;
            for (int p = w; p < CHUNK; p += 4) {
                int pc = s_code[p];
                if (pc & (1 << 15)) {
                    if (lane < EE) {
                        float xv = s_buf[p * PXE + lane];
                        #pragma unroll
                        for (int g = 0; g < GG; g++) {
                            int c = (pc >> (3 * g)) & 7;
                            atomicAdd(&s_csum[g][c][lane], xv);
                        }
                    }
                }
            }
        }
        __syncthreads();
    }

    // ---------------- phase 2: long-term interest -> feat[128:176] ----------------
    if (tid < EE) {
        float acc = 0.f;
        #pragma unroll
        for (int g = 0; g < GG; g++) {
            int c = s_icode[g];
            acc += s_csum[g][c][tid] / fmaxf(s_vc[g][c], 1.0f);   // vc==0 => csum==0 => 0
        }
        s_feat[128 + tid] = acc * 0.25f;
    }

    // ---------------- phase 3: short-term attention ----------------
    float* Xs   = s_buf;                 // [64][PXE]
    float* wkq  = s_buf + SLEN * PXE;    // [48][8]
    float* bkq  = wkq + EE * NHH;        // [8]
    float* sc   = bkq + NHH;             // scores/attn [8][64]
    float* su   = sc + NHH * SLEN;       // [8][48]
    float* sctx = su + NHH * EE;         // [32]

    for (int f = tid; f < SLEN * EE; f += 256) {
        int p = f / EE, e = f - p * EE;
        int fe = e >> 4;
        const int* idp = (fe == 0) ? st_g : (fe == 1) ? st_s : st_c;
        int id = idp[b * SLEN + p];
        Xs[p * PXE + e] = ldf<BF16>(tbl, id * EMBD + (e & 15));
    }
    if (tid < 64) {
        unsigned long long msk = __ballot(st_g[b * SLEN + tid] != 0);
        if (tid == 0) s_len = __popcll(msk);
    }
    // fold wk through q: wkq[e][h] = sum_d wk[e][h][d] * q[h][d]
    for (int t = tid; t < EE * NHH; t += 256) {
        int e = t >> 3, h = t & 7;
        float acc = 0.f;
        #pragma unroll
        for (int d = 0; d < KDD; d++) acc += ldf<BF16>(wk, e * 32 + h * 4 + d) * s_q[h * 4 + d];
        wkq[t] = acc;
    }
    if (tid < NHH) {
        float acc = 0.f;
        #pragma unroll
        for (int d = 0; d < KDD; d++) acc += ldf<BF16>(bk, tid * 4 + d) * s_q[tid * 4 + d];
        bkq[tid] = acc;
    }
    __syncthreads();
    // scores
    for (int t = tid; t < NHH * SLEN; t += 256) {
        int h = t >> 6, s = t & 63;
        float acc = bkq[h];
        for (int e = 0; e < EE; e++) acc += Xs[s * PXE + e] * wkq[e * NHH + h];
        acc *= 0.5f;                      // 1/sqrt(KD)
        if (s >= s_len) acc -= 1e9f;
        sc[h * SLEN + s] = acc;
    }
    __syncthreads();
    // softmax per head (wave per head, lane = s)
    {
        const int w = tid >> 6, lane = tid & 63;
        for (int h = w; h < NHH; h += 4) {
            float v = sc[h * SLEN + lane];
            float mx = v;
            #pragma unroll
            for (int o = 32; o; o >>= 1) mx = fmaxf(mx, __shfl_xor(mx, o));
            float ex = __expf(v - mx);
            float sm = ex;
            #pragma unroll
            for (int o = 32; o; o >>= 1) sm += __shfl_xor(sm, o);
            sc[h * SLEN + lane] = ex / sm;
        }
    }
    __syncthreads();
    // u[h][e] = sum_s attn[h][s] * Xs[s][e]
    for (int t = tid; t < NHH * EE; t += 256) {
        int h = t / EE, e = t - h * EE;
        float acc = 0.f;
        for (int s = 0; s < SLEN; s++) acc += sc[h * SLEN + s] * Xs[s * PXE + e];
        su[t] = acc;
    }
    __syncthreads();
    // ctx[h][d] = sum_e u[h][e]*wv[e][h][d] + bv  (sum attn == 1)
    if (tid < 32) {
        float acc = ldf<BF16>(bv, tid);
        int h = tid >> 2;
        for (int e = 0; e < EE; e++) acc += su[h * EE + e] * ldf<BF16>(wv, e * 32 + tid);
        sctx[tid] = acc;
    }
    __syncthreads();
    // st[e] = sum_{h,d} ctx * wo + bo -> feat[176:224]
    if (tid < EE) {
        float acc = ldf<BF16>(bo, tid);
        #pragma unroll
        for (int i = 0; i < 32; i++) acc += sctx[i] * ldf<BF16>(wo, i * EE + tid);
        s_feat[176 + tid] = acc;
    }
    __syncthreads();

    // ---------------- phase 4: MLP 224 -> 200(LN,relu) -> 80(LN,relu) -> 1(sigmoid) ----------------
    float z1 = 0.f;
    if (tid < H1D) {
        z1 = ldf<BF16>(b1, tid);
        for (int i = 0; i < INDIM; i++) z1 += s_feat[i] * ldf<BF16>(w1, i * H1D + tid);
        s_buf[tid] = z1;
    }
    __syncthreads();
    if (tid < 64) {
        float sm = 0.f, sq = 0.f;
        for (int j = tid; j < H1D; j += 64) { float v = s_buf[j]; sm += v; sq += v * v; }
        #pragma unroll
        for (int o = 32; o; o >>= 1) { sm += __shfl_xor(sm, o); sq += __shfl_xor(sq, o); }
        if (tid == 0) { float mu = sm / H1D; s_mu = mu; s_rstd = rsqrtf(sq / H1D - mu * mu + 1e-3f); }
    }
    __syncthreads();
    if (tid < H1D) {
        float h = fmaxf(ldf<BF16>(g1, tid) * (z1 - s_mu) * s_rstd + ldf<BF16>(be1, tid), 0.f);
        s_buf[256 + tid] = h;
    }
    __syncthreads();
    float z2 = 0.f;
    if (tid < H2D) {
        z2 = ldf<BF16>(b2, tid);
        for (int i = 0; i < H1D; i++) z2 += s_buf[256 + i] * ldf<BF16>(w2, i * H2D + tid);
        s_buf[tid] = z2;
    }
    __syncthreads();
    if (tid < 64) {
        float sm = 0.f, sq = 0.f;
        for (int j = tid; j < H2D; j += 64) { float v = s_buf[j]; sm += v; sq += v * v; }
        #pragma unroll
        for (int o = 32; o; o >>= 1) { sm += __shfl_xor(sm, o); sq += __shfl_xor(sq, o); }
        if (tid == 0) { float mu = sm / H2D; s_mu = mu; s_rstd = rsqrtf(sq / H2D - mu * mu + 1e-3f); }
    }
    __syncthreads();
    if (tid < H2D) {
        float h = fmaxf(ldf<BF16>(g2, tid) * (z2 - s_mu) * s_rstd + ldf<BF16>(be2, tid), 0.f);
        s_red[tid] = h * ldf<BF16>(w3, tid);
    }
    __syncthreads();
    if (tid == 0) {
        float acc = ldf<BF16>(b3, 0);
        for (int i = 0; i < H2D; i++) acc += s_red[i];
        float sig = 1.f / (1.f + __expf(-acc));
        if constexpr (BF16) ((__hip_bfloat16*)outp)[b] = __float2bfloat16(sig);
        else                ((float*)outp)[b] = sig;
    }
}

extern "C" void kernel_launch(void* const* d_in, const int* in_sizes, int n_in,
                              void* d_out, int out_size, void* d_ws, size_t ws_size,
                              hipStream_t stream) {
    const int B = in_sizes[0];   // batch = 1024
    int* flag = (ws_size >= 4) ? (int*)d_ws : nullptr;
    if (flag) detect_dtype<<<1, 64, 0, stream>>>((const unsigned short*)d_in[14], flag);

#define ARGS \
        (const int*)d_in[0],  (const int*)d_in[1],  (const int*)d_in[2],              \
        (const int*)d_in[3],  (const int*)d_in[4],                                    \
        (const int*)d_in[5],  (const int*)d_in[6],  (const int*)d_in[7],              \
        (const int*)d_in[8],  (const int*)d_in[9],  (const int*)d_in[10],             \
        (const int*)d_in[11], (const int*)d_in[12], (const int*)d_in[13],             \
        (const void*)d_in[14], (const void*)d_in[15],                                 \
        (const void*)d_in[16], (const void*)d_in[17],                                 \
        (const void*)d_in[18], (const void*)d_in[19],                                 \
        (const void*)d_in[20], (const void*)d_in[21],                                 \
        (const void*)d_in[22], (const void*)d_in[23],                                 \
        (const void*)d_in[24], (const void*)d_in[25],                                 \
        (const void*)d_in[26], (const void*)d_in[27],                                 \
        (const void*)d_in[28], (const void*)d_in[29],                                 \
        (const void*)d_in[30], (const void*)d_in[31],                                 \
        (const void*)d_in[32], (const void*)d_in[33],                                 \
        d_out, flag

    sdim_fwd<false><<<B, 256, 0, stream>>>(ARGS);
    sdim_fwd<true ><<<B, 256, 0, stream>>>(ARGS);
#undef ARGS
}

// Round 3
// 571.372 us; speedup vs baseline: 1.0385x; 1.0385x over previous
//
#include <hip/hip_runtime.h>
#include <hip/hip_bf16.h>

#define LLEN 512
#define SLEN 64
#define EMBD 16
#define EE 48
#define GG 4
#define MMB 3
#define NHH 8
#define KDD 4
#define INDIM 224
#define H1D 200
#define H2D 80
#define CHUNK 128
#define PXE 52   // padded row stride (floats): 208B, 16B-aligned, odd multiple of 4 -> spreads banks

__device__ __forceinline__ float bf2f(unsigned short u) {
    union { unsigned int i; float f; } v; v.i = ((unsigned int)u) << 16; return v.f;
}

template<bool BF16>
__device__ __forceinline__ float ldf(const void* p, int i) {
    if constexpr (BF16) return bf2f(((const unsigned short*)p)[i]);
    else                return ((const float*)p)[i];
}

// load 4 consecutive elements starting at element index i4 (multiple of 4)
template<bool BF16>
__device__ __forceinline__ float4 ld4(const void* p, int i4) {
    if constexpr (BF16) {
        ushort4 u = ((const ushort4*)p)[i4 >> 2];
        return make_float4(bf2f(u.x), bf2f(u.y), bf2f(u.z), bf2f(u.w));
    } else {
        return ((const float4*)p)[i4 >> 2];
    }
}

// ---- dtype detection (see R1 notes): even ushort indices of a bf16 tensor are
// small values (exp<127); of fp32 they are random mantissa bits.
__global__ void detect_dtype(const unsigned short* __restrict__ tbl, int* __restrict__ flag) {
    int t = threadIdx.x;
    int big = 0;
    for (int i = t; i < 128; i += 64) {
        unsigned short u = tbl[2 * i];
        int ex = (u >> 7) & 0xFF;
        if (ex >= 127) big = 1;
    }
    unsigned long long m = __ballot(big);
    if (t == 0) flag[0] = (m == 0ull) ? 1 : 0;   // 1 => bf16, 0 => fp32
}

template<bool BF16>
__global__ __launch_bounds__(256) void sdim_fwd(
    const int* __restrict__ uid, const int* __restrict__ ut1, const int* __restrict__ ut2,
    const int* __restrict__ ut3, const int* __restrict__ ut4,
    const int* __restrict__ lb_g, const int* __restrict__ lb_s, const int* __restrict__ lb_c,
    const int* __restrict__ lt_g, const int* __restrict__ lt_s, const int* __restrict__ lt_c,
    const int* __restrict__ st_g, const int* __restrict__ st_s, const int* __restrict__ st_c,
    const void* __restrict__ tbl, const void* __restrict__ Hm,
    const void* __restrict__ wq, const void* __restrict__ bq,
    const void* __restrict__ wk, const void* __restrict__ bk,
    const void* __restrict__ wv, const void* __restrict__ bv,
    const void* __restrict__ wo, const void* __restrict__ bo,
    const void* __restrict__ w1, const void* __restrict__ b1,
    const void* __restrict__ g1, const void* __restrict__ be1,
    const void* __restrict__ w2, const void* __restrict__ b2,
    const void* __restrict__ g2, const void* __restrict__ be2,
    const void* __restrict__ w3, const void* __restrict__ b3,
    void* __restrict__ outp, const int* __restrict__ flagp)
{
    // uniform early-exit: only the instantiation matching the detected dtype runs
    if (flagp) { if (flagp[0] != (BF16 ? 1 : 0)) return; }
    else       { if (BF16) return; }

    const int b = blockIdx.x;
    const int tid = threadIdx.x;

    // sHr[part][k][j][jj] = H[e=4k+jj][part*6+j]   (2*12*6*4 = 576 floats)
    __shared__ alignas(16) float sHr[576];
    __shared__ float s_csum[GG][8][EE];               // bucket sums
    __shared__ float s_vc[GG][8];                     // bucket counts (incl. padded)
    __shared__ float s_feat[INDIM];                   // final 224-d feature
    __shared__ float s_q[NHH * KDD];
    __shared__ float s_red[128];
    __shared__ int   s_icode[GG];
    __shared__ int   s_len;
    __shared__ float s_mu, s_rstd;
    __shared__ alignas(16) float s_buf[CHUNK * PXE];  // 6656 floats
    __shared__ int   s_code[CHUNK];

    // ---------------- phase 0: H -> LDS (repacked), zero buckets, Xu/Xi embeds ----------------
    for (int i = tid; i < 576; i += 256) {
        int jj = i & 3, r = i >> 2;            // r = part*72 + k*6 + j
        int j = r % 6, kk = (r / 6) % 12, part = r / 72;
        sHr[i] = ldf<BF16>(Hm, (4 * kk + jj) * 12 + part * 6 + j);
    }
    for (int i = tid; i < GG * 8 * EE; i += 256) ((float*)s_csum)[i] = 0.f;
    if (tid < GG * 8) ((float*)s_vc)[tid] = 0.f;
    if (tid < 80) {
        int f = tid >> 4, e = tid & 15;
        int id = (f == 0) ? uid[b] : (f == 1) ? ut1[b] : (f == 2) ? ut2[b] : (f == 3) ? ut3[b] : ut4[b];
        s_feat[tid] = ldf<BF16>(tbl, id * EMBD + e);
    } else if (tid < 128) {
        int t = tid - 80; int f = t >> 4, e = t & 15;
        int id = (f == 0) ? lb_g[b] : (f == 1) ? lb_s[b] : lb_c[b];
        s_feat[80 + t] = ldf<BF16>(tbl, id * EMBD + e);
    }
    __syncthreads();

    // ---------------- phase 0.5: q projection + item LSH projections ----------------
    if (tid < 32) {
        float acc = ldf<BF16>(bq, tid);
        for (int e = 0; e < EE; e++) acc += s_feat[80 + e] * ldf<BF16>(wq, e * 32 + tid);
        s_q[tid] = acc;
    }
    if (tid >= 64 && tid < 64 + GG * MMB) {
        int t = tid - 64;                      // t = g*3+m = part*6+j
        int part = t / 6, j = t % 6;
        float acc = 0.f;
        for (int e = 0; e < EE; e++)
            acc += s_feat[80 + e] * sHr[(part * 72 + (e >> 2) * 6 + j) * 4 + (e & 3)];
        s_red[t] = acc;
    }
    __syncthreads();
    if (tid < GG) {
        int code = 0;
        #pragma unroll
        for (int m = 0; m < MMB; m++) if (s_red[tid * 3 + m] > 0.f) code |= (1 << m);
        s_icode[tid] = code;
    }

    // ---------------- phase 1: long-term, 4 chunks of 128 positions ----------------
    for (int ch = 0; ch < LLEN / CHUNK; ch++) {
        const int base = ch * CHUNK;
        // A: pipelined gather: ids -> gathers -> LDS stores (all-static indexing)
        int ids[6];
        #pragma unroll
        for (int i = 0; i < 6; i++) {
            int f = tid + 256 * i;
            int p = f / 12, q = f - 12 * p, fe = q >> 2;
            const int* idp = (fe == 0) ? lt_g : (fe == 1) ? lt_s : lt_c;
            ids[i] = idp[b * LLEN + base + p];
        }
        float4 vs[6];
        #pragma unroll
        for (int i = 0; i < 6; i++) {
            int f = tid + 256 * i;
            int p = f / 12, q = f - 12 * p;
            vs[i] = ld4<BF16>(tbl, ids[i] * EMBD + ((q & 3) << 2));
        }
        if (tid < CHUNK) s_code[tid] = 0;
        #pragma unroll
        for (int i = 0; i < 6; i++) {
            int f = tid + 256 * i;
            int p = f / 12, q = f - 12 * p;
            *(float4*)&s_buf[p * PXE + (q << 2)] = vs[i];
        }
        __syncthreads();
        // B: LSH codes — 2 threads per position (part = low bit), 6 accumulators each.
        {
            const int p = tid >> 1, part = tid & 1;
            const float4* xr = (const float4*)&s_buf[p * PXE];
            const float4* hp = (const float4*)&sHr[part * 288];   // [k][j][4]
            float acc0 = 0.f, acc1 = 0.f, acc2 = 0.f, acc3 = 0.f, acc4 = 0.f, acc5 = 0.f;
            #pragma unroll
            for (int k = 0; k < 12; k++) {
                float4 x4 = xr[k];
                float4 h0 = hp[k * 6 + 0], h1 = hp[k * 6 + 1], h2 = hp[k * 6 + 2];
                float4 h3 = hp[k * 6 + 3], h4 = hp[k * 6 + 4], h5 = hp[k * 6 + 5];
                acc0 += x4.x * h0.x + x4.y * h0.y + x4.z * h0.z + x4.w * h0.w;
                acc1 += x4.x * h1.x + x4.y * h1.y + x4.z * h1.z + x4.w * h1.w;
                acc2 += x4.x * h2.x + x4.y * h2.y + x4.z * h2.z + x4.w * h2.w;
                acc3 += x4.x * h3.x + x4.y * h3.y + x4.z * h3.z + x4.w * h3.w;
                acc4 += x4.x * h4.x + x4.y * h4.y + x4.z * h4.z + x4.w * h4.w;
                acc5 += x4.x * h5.x + x4.y * h5.y + x4.z * h5.z + x4.w * h5.w;
            }
            int c0 = (acc0 > 0.f ? 1 : 0) | (acc1 > 0.f ? 2 : 0) | (acc2 > 0.f ? 4 : 0);
            int c1 = (acc3 > 0.f ? 1 : 0) | (acc4 > 0.f ? 2 : 0) | (acc5 > 0.f ? 4 : 0);
            int g0 = 2 * part, g1 = 2 * part + 1;
            atomicAdd(&s_vc[g0][c0], 1.0f);   // counts include padded positions (ref semantics)
            atomicAdd(&s_vc[g1][c1], 1.0f);
            int pk = (c0 << (3 * g0)) | (c1 << (3 * g1));
            if (part == 0) {
                int valid = (lt_g[b * LLEN + base + p] != 0) ? 1 : 0;
                pk |= valid << 15;
            }
            atomicOr(&s_code[p], pk);
        }
        __syncthreads();
        // C: masked scatter-add, lane = e (wave-uniform position loop)
        {
            const int w = tid >> 6, lane = tid & 63;
            for (int p = w; p < CHUNK; p += 4) {
                int pc = s_code[p];
                if (pc & (1 << 15)) {
                    if (lane < EE) {
                        float xv = s_buf[p * PXE + lane];
                        #pragma unroll
                        for (int g = 0; g < GG; g++) {
                            int c = (pc >> (3 * g)) & 7;
                            atomicAdd(&s_csum[g][c][lane], xv);
                        }
                    }
                }
            }
        }
        __syncthreads();
    }

    // ---------------- phase 2: long-term interest -> feat[128:176] ----------------
    if (tid < EE) {
        float acc = 0.f;
        #pragma unroll
        for (int g = 0; g < GG; g++) {
            int c = s_icode[g];
            acc += s_csum[g][c][tid] / fmaxf(s_vc[g][c], 1.0f);   // vc==0 => csum==0 => 0
        }
        s_feat[128 + tid] = acc * 0.25f;
    }

    // ---------------- phase 3: short-term attention ----------------
    float* Xs   = s_buf;                 // [64][PXE]
    float* wkq  = s_buf + SLEN * PXE;    // [48][8]
    float* bkq  = wkq + EE * NHH;        // [8]
    float* sc   = bkq + NHH;             // scores/attn [8][64]
    float* su   = sc + NHH * SLEN;       // [8][48]
    float* sctx = su + NHH * EE;         // [32]

    {   // pipelined short-term gather (768 float4 units = 3 iters x 256 threads)
        int ids[3];
        #pragma unroll
        for (int i = 0; i < 3; i++) {
            int f = tid + 256 * i;
            int p = f / 12, q = f - 12 * p, fe = q >> 2;
            const int* idp = (fe == 0) ? st_g : (fe == 1) ? st_s : st_c;
            ids[i] = idp[b * SLEN + p];
        }
        float4 vs[3];
        #pragma unroll
        for (int i = 0; i < 3; i++) {
            int f = tid + 256 * i;
            int p = f / 12, q = f - 12 * p;
            vs[i] = ld4<BF16>(tbl, ids[i] * EMBD + ((q & 3) << 2));
        }
        #pragma unroll
        for (int i = 0; i < 3; i++) {
            int f = tid + 256 * i;
            int p = f / 12, q = f - 12 * p;
            *(float4*)&Xs[p * PXE + (q << 2)] = vs[i];
        }
    }
    if (tid < 64) {
        unsigned long long msk = __ballot(st_g[b * SLEN + tid] != 0);
        if (tid == 0) s_len = __popcll(msk);
    }
    // fold wk through q: wkq[e][h] = sum_d wk[e][h][d] * q[h][d]
    for (int t = tid; t < EE * NHH; t += 256) {
        int e = t >> 3, h = t & 7;
        float acc = 0.f;
        #pragma unroll
        for (int d = 0; d < KDD; d++) acc += ldf<BF16>(wk, e * 32 + h * 4 + d) * s_q[h * 4 + d];
        wkq[t] = acc;
    }
    if (tid < NHH) {
        float acc = 0.f;
        #pragma unroll
        for (int d = 0; d < KDD; d++) acc += ldf<BF16>(bk, tid * 4 + d) * s_q[tid * 4 + d];
        bkq[tid] = acc;
    }
    __syncthreads();
    // scores
    for (int t = tid; t < NHH * SLEN; t += 256) {
        int h = t >> 6, s = t & 63;
        float acc = bkq[h];
        for (int e = 0; e < EE; e++) acc += Xs[s * PXE + e] * wkq[e * NHH + h];
        acc *= 0.5f;                      // 1/sqrt(KD)
        if (s >= s_len) acc -= 1e9f;
        sc[h * SLEN + s] = acc;
    }
    __syncthreads();
    // softmax per head (wave per head, lane = s)
    {
        const int w = tid >> 6, lane = tid & 63;
        for (int h = w; h < NHH; h += 4) {
            float v = sc[h * SLEN + lane];
            float mx = v;
            #pragma unroll
            for (int o = 32; o; o >>= 1) mx = fmaxf(mx, __shfl_xor(mx, o));
            float ex = __expf(v - mx);
            float sm = ex;
            #pragma unroll
            for (int o = 32; o; o >>= 1) sm += __shfl_xor(sm, o);
            sc[h * SLEN + lane] = ex / sm;
        }
    }
    __syncthreads();
    // u[h][e] = sum_s attn[h][s] * Xs[s][e]
    for (int t = tid; t < NHH * EE; t += 256) {
        int h = t / EE, e = t - h * EE;
        float acc = 0.f;
        for (int s = 0; s < SLEN; s++) acc += sc[h * SLEN + s] * Xs[s * PXE + e];
        su[t] = acc;
    }
    __syncthreads();
    // ctx[h][d] = sum_e u[h][e]*wv[e][h][d] + bv  (sum attn == 1)
    if (tid < 32) {
        float acc = ldf<BF16>(bv, tid);
        int h = tid >> 2;
        for (int e = 0; e < EE; e++) acc += su[h * EE + e] * ldf<BF16>(wv, e * 32 + tid);
        sctx[tid] = acc;
    }
    __syncthreads();
    // st[e] = sum_{h,d} ctx * wo + bo -> feat[176:224]
    if (tid < EE) {
        float acc = ldf<BF16>(bo, tid);
        #pragma unroll
        for (int i = 0; i < 32; i++) acc += sctx[i] * ldf<BF16>(wo, i * EE + tid);
        s_feat[176 + tid] = acc;
    }
    __syncthreads();

    // ---------------- phase 4: MLP 224 -> 200(LN,relu) -> 80(LN,relu) -> 1(sigmoid) ----------------
    float z1 = 0.f;
    if (tid < H1D) {
        z1 = ldf<BF16>(b1, tid);
        for (int i = 0; i < INDIM; i++) z1 += s_feat[i] * ldf<BF16>(w1, i * H1D + tid);
        s_buf[tid] = z1;
    }
    __syncthreads();
    if (tid < 64) {
        float sm = 0.f, sq = 0.f;
        for (int j = tid; j < H1D; j += 64) { float v = s_buf[j]; sm += v; sq += v * v; }
        #pragma unroll
        for (int o = 32; o; o >>= 1) { sm += __shfl_xor(sm, o); sq += __shfl_xor(sq, o); }
        if (tid == 0) { float mu = sm / H1D; s_mu = mu; s_rstd = rsqrtf(sq / H1D - mu * mu + 1e-3f); }
    }
    __syncthreads();
    if (tid < H1D) {
        float h = fmaxf(ldf<BF16>(g1, tid) * (z1 - s_mu) * s_rstd + ldf<BF16>(be1, tid), 0.f);
        s_buf[256 + tid] = h;
    }
    __syncthreads();
    float z2 = 0.f;
    if (tid < H2D) {
        z2 = ldf<BF16>(b2, tid);
        for (int i = 0; i < H1D; i++) z2 += s_buf[256 + i] * ldf<BF16>(w2, i * H2D + tid);
        s_buf[tid] = z2;
    }
    __syncthreads();
    if (tid < 64) {
        float sm = 0.f, sq = 0.f;
        for (int j = tid; j < H2D; j += 64) { float v = s_buf[j]; sm += v; sq += v * v; }
        #pragma unroll
        for (int o = 32; o; o >>= 1) { sm += __shfl_xor(sm, o); sq += __shfl_xor(sq, o); }
        if (tid == 0) { float mu = sm / H2D; s_mu = mu; s_rstd = rsqrtf(sq / H2D - mu * mu + 1e-3f); }
    }
    __syncthreads();
    if (tid < H2D) {
        float h = fmaxf(ldf<BF16>(g2, tid) * (z2 - s_mu) * s_rstd + ldf<BF16>(be2, tid), 0.f);
        s_red[tid] = h * ldf<BF16>(w3, tid);
    }
    __syncthreads();
    if (tid == 0) {
        float acc = ldf<BF16>(b3, 0);
        for (int i = 0; i < H2D; i++) acc += s_red[i];
        float sig = 1.f / (1.f + __expf(-acc));
        if constexpr (BF16) ((__hip_bfloat16*)outp)[b] = __float2bfloat16(sig);
        else                ((float*)outp)[b] = sig;
    }
}

extern "C" void kernel_launch(void* const* d_in, const int* in_sizes, int n_in,
                              void* d_out, int out_size, void* d_ws, size_t ws_size,
                              hipStream_t stream) {
    const int B = in_sizes[0];   // batch = 1024
    int* flag = (ws_size >= 4) ? (int*)d_ws : nullptr;
    if (flag) detect_dtype<<<1, 64, 0, stream>>>((const unsigned short*)d_in[14], flag);

#define ARGS \
        (const int*)d_in[0],  (const int*)d_in[1],  (const int*)d_in[2],              \
        (const int*)d_in[3],  (const int*)d_in[4],                                    \
        (const int*)d_in[5],  (const int*)d_in[6],  (const int*)d_in[7],              \
        (const int*)d_in[8],  (const int*)d_in[9],  (const int*)d_in[10],             \
        (const int*)d_in[11], (const int*)d_in[12], (const int*)d_in[13],             \
        (const void*)d_in[14], (const void*)d_in[15],                                 \
        (const void*)d_in[16], (const void*)d_in[17],                                 \
        (const void*)d_in[18], (const void*)d_in[19],                                 \
        (const void*)d_in[20], (const void*)d_in[21],                                 \
        (const void*)d_in[22], (const void*)d_in[23],                                 \
        (const void*)d_in[24], (const void*)d_in[25],                                 \
        (const void*)d_in[26], (const void*)d_in[27],                                 \
        (const void*)d_in[28], (const void*)d_in[29],                                 \
        (const void*)d_in[30], (const void*)d_in[31],                                 \
        (const void*)d_in[32], (const void*)d_in[33],                                 \
        d_out, flag

    sdim_fwd<false><<<B, 256, 0, stream>>>(ARGS);
    sdim_fwd<true ><<<B, 256, 0, stream>>>(ARGS);
#undef ARGS
}

// Round 5
// 291.681 us; speedup vs baseline: 2.0343x; 1.9589x over previous
//
#include <hip/hip_runtime.h>
#include <hip/hip_bf16.h>

#define LLEN 512
#define SLEN 64
#define EMBD 16
#define EE 48
#define GG 4
#define MMB 3
#define NHH 8
#define KDD 4
#define INDIM 224
#define H1D 200
#define H2D 80
#define CHUNK 128
#define PXE 52   // padded row stride (floats)

__device__ __forceinline__ float bf2f(unsigned short u) {
    union { unsigned int i; float f; } v; v.i = ((unsigned int)u) << 16; return v.f;
}

template<bool BF16>
__device__ __forceinline__ float ldf(const void* p, int i) {
    if constexpr (BF16) return bf2f(((const unsigned short*)p)[i]);
    else                return ((const float*)p)[i];
}

template<bool BF16>
__device__ __forceinline__ float4 ld4(const void* p, int i4) {
    if constexpr (BF16) {
        ushort4 u = ((const ushort4*)p)[i4 >> 2];
        return make_float4(bf2f(u.x), bf2f(u.y), bf2f(u.z), bf2f(u.w));
    } else {
        return ((const float4*)p)[i4 >> 2];
    }
}

// H value: prefer fp32 workspace copy (uniform scalar loads); fallback to global.
template<bool BF16>
__device__ __forceinline__ float ldh(const float* hf, const void* Hm, int i) {
    return hf ? hf[i] : ldf<BF16>(Hm, i);
}

// ---- prep: dtype detection + H -> fp32 in workspace.
__global__ void prep_kernel(const unsigned short* __restrict__ tbl,
                            const void* __restrict__ Hm,
                            int* __restrict__ flag, float* __restrict__ hf) {
    int t = threadIdx.x;   // 64
    int big = 0;
    for (int i = t; i < 128; i += 64) {
        unsigned short u = tbl[2 * i];
        int ex = (u >> 7) & 0xFF;
        if (ex >= 127) big = 1;
    }
    unsigned long long m = __ballot(big);
    int isbf = (m == 0ull) ? 1 : 0;
    if (t == 0) flag[0] = isbf;
    for (int i = t; i < EE * 12; i += 64)
        hf[i] = isbf ? bf2f(((const unsigned short*)Hm)[i]) : ((const float*)Hm)[i];
}

template<bool BF16>
__global__ __launch_bounds__(256, 4) void sdim_fwd(
    const int* __restrict__ uid, const int* __restrict__ ut1, const int* __restrict__ ut2,
    const int* __restrict__ ut3, const int* __restrict__ ut4,
    const int* __restrict__ lb_g, const int* __restrict__ lb_s, const int* __restrict__ lb_c,
    const int* __restrict__ lt_g, const int* __restrict__ lt_s, const int* __restrict__ lt_c,
    const int* __restrict__ st_g, const int* __restrict__ st_s, const int* __restrict__ st_c,
    const void* __restrict__ tbl, const void* __restrict__ Hm,
    const void* __restrict__ wq, const void* __restrict__ bq,
    const void* __restrict__ wk, const void* __restrict__ bk,
    const void* __restrict__ wv, const void* __restrict__ bv,
    const void* __restrict__ wo, const void* __restrict__ bo,
    const void* __restrict__ w1, const void* __restrict__ b1,
    const void* __restrict__ g1, const void* __restrict__ be1,
    const void* __restrict__ w2, const void* __restrict__ b2,
    const void* __restrict__ g2, const void* __restrict__ be2,
    const void* __restrict__ w3, const void* __restrict__ b3,
    void* __restrict__ outp, const int* __restrict__ flagp, const float* __restrict__ hf)
{
    if (flagp) { if (flagp[0] != (BF16 ? 1 : 0)) return; }
    else       { if (BF16) return; }

    const int b = blockIdx.x;
    const int tid = threadIdx.x;
    const int lane = tid & 63;
    const int wid = __builtin_amdgcn_readfirstlane(tid >> 6);   // wave id 0..3, uniform

    __shared__ float s_csum[GG][8][EE];               // bucket sums (written once, after chunk loop)
    __shared__ float s_vc[GG][8];                     // bucket counts (incl. padded)
    __shared__ float s_feat[INDIM];                   // final 224-d feature
    __shared__ float s_q[NHH * KDD];
    __shared__ float s_red[128];
    __shared__ int   s_icode[GG];
    __shared__ int   s_len;
    __shared__ float s_mu, s_rstd;
    __shared__ alignas(16) float s_buf[CHUNK * PXE + 16];
    __shared__ int   s_code[CHUNK];

    // ---------------- phase 0: Xu/Xi embeds -> feat ----------------
    if (tid < 80) {
        int f = tid >> 4, e = tid & 15;
        int id = (f == 0) ? uid[b] : (f == 1) ? ut1[b] : (f == 2) ? ut2[b] : (f == 3) ? ut3[b] : ut4[b];
        s_feat[tid] = ldf<BF16>(tbl, id * EMBD + e);
    } else if (tid < 128) {
        int t = tid - 80; int f = t >> 4, e = t & 15;
        int id = (f == 0) ? lb_g[b] : (f == 1) ? lb_s[b] : lb_c[b];
        s_feat[80 + t] = ldf<BF16>(tbl, id * EMBD + e);
    }
    __syncthreads();

    // ---------------- phase 0.5: q projection + item LSH codes ----------------
    if (tid < 32) {
        float acc = ldf<BF16>(bq, tid);
        for (int e = 0; e < EE; e++) acc += s_feat[80 + e] * ldf<BF16>(wq, e * 32 + tid);
        s_q[tid] = acc;
    }
    if (tid >= 64 && tid < 64 + GG * MMB) {
        int j = tid - 64;
        float acc = 0.f;
        for (int e = 0; e < EE; e++) acc += s_feat[80 + e] * ldh<BF16>(hf, Hm, e * 12 + j);
        s_red[j] = acc;
    }
    __syncthreads();
    if (tid < GG) {
        int code = 0;
        #pragma unroll
        for (int m = 0; m < MMB; m++) if (s_red[tid * 3 + m] > 0.f) code |= (1 << m);
        s_icode[tid] = code;
    }

    // ---------------- phase 1: long-term, 4 chunks of 128 positions ----------------
    // Per-wave register bucket accumulators (wave wid owns group g=wid), zero atomics.
    float a0 = 0.f, a1 = 0.f, a2 = 0.f, a3 = 0.f, a4 = 0.f, a5 = 0.f, a6 = 0.f, a7 = 0.f;
    int   n0 = 0,   n1 = 0,   n2 = 0,   n3 = 0,   n4 = 0,   n5 = 0,   n6 = 0,   n7 = 0;

    for (int ch = 0; ch < LLEN / CHUNK; ch++) {
        const int base = ch * CHUNK;
        // A: pipelined gather: ids -> gathers -> LDS stores
        {
            int ids[6];
            #pragma unroll
            for (int i = 0; i < 6; i++) {
                int f = tid + 256 * i;
                int p = f / 12, q = f - 12 * p, fe = q >> 2;
                const int* idp = (fe == 0) ? lt_g : (fe == 1) ? lt_s : lt_c;
                ids[i] = idp[b * LLEN + base + p];
            }
            float4 vs[6];
            #pragma unroll
            for (int i = 0; i < 6; i++) {
                int f = tid + 256 * i;
                int p = f / 12, q = f - 12 * p;
                vs[i] = ld4<BF16>(tbl, ids[i] * EMBD + ((q & 3) << 2));
            }
            #pragma unroll
            for (int i = 0; i < 6; i++) {
                int f = tid + 256 * i;
                int p = f / 12, q = f - 12 * p;
                *(float4*)&s_buf[p * PXE + (q << 2)] = vs[i];
            }
        }
        __syncthreads();
        // B: LSH codes, one thread per position (waves 0 and 2), H from fp32 workspace
        // via compile-time-uniform indices -> scalar loads. All-static acc indexing.
        if (!(wid & 1)) {
            const int p = (tid & 63) | ((wid >> 1) << 6);
            float acc[12];
            #pragma unroll
            for (int j = 0; j < 12; j++) acc[j] = 0.f;
            #pragma unroll
            for (int k = 0; k < 12; k++) {
                float4 x4 = *(const float4*)&s_buf[p * PXE + 4 * k];
                #pragma unroll
                for (int j = 0; j < 12; j++) {
                    acc[j] += x4.x * ldh<BF16>(hf, Hm, (4 * k + 0) * 12 + j)
                            + x4.y * ldh<BF16>(hf, Hm, (4 * k + 1) * 12 + j)
                            + x4.z * ldh<BF16>(hf, Hm, (4 * k + 2) * 12 + j)
                            + x4.w * ldh<BF16>(hf, Hm, (4 * k + 3) * 12 + j);
                }
            }
            int pk = 0;
            #pragma unroll
            for (int g = 0; g < GG; g++) {
                int code = 0;
                #pragma unroll
                for (int m = 0; m < MMB; m++) if (acc[g * 3 + m] > 0.f) code |= (1 << m);
                pk |= code << (3 * g);
            }
            int valid = (lt_g[b * LLEN + base + p] != 0) ? 1 : 0;
            s_code[p] = pk | (valid << 15);
        }
        __syncthreads();
        // C: bucket accumulation, wave wid owns g=wid. Codes preloaded to VGPRs, extracted
        // per position via v_readlane (literal lane) -> SGPR -> scalar branch chain.
        {
            int cv0 = s_code[lane];
            int cv1 = s_code[64 + lane];
            #pragma unroll
            for (int ph = 0; ph < 2; ph++) {
                #pragma unroll
                for (int pp = 0; pp < 64; pp++) {
                    int pk = __builtin_amdgcn_readlane(ph == 0 ? cv0 : cv1, pp);
                    float xv = s_buf[(ph * 64 + pp) * PXE + lane];  // lanes 48..63 read pad, discarded
                    int cc = (pk >> (3 * wid)) & 7;
                    int vld = pk & (1 << 15);
                    if (cc == 0)      { n0++; if (vld) a0 += xv; }
                    else if (cc == 1) { n1++; if (vld) a1 += xv; }
                    else if (cc == 2) { n2++; if (vld) a2 += xv; }
                    else if (cc == 3) { n3++; if (vld) a3 += xv; }
                    else if (cc == 4) { n4++; if (vld) a4 += xv; }
                    else if (cc == 5) { n5++; if (vld) a5 += xv; }
                    else if (cc == 6) { n6++; if (vld) a6 += xv; }
                    else              { n7++; if (vld) a7 += xv; }
                }
            }
        }
        __syncthreads();
    }
    // flush per-wave bucket registers -> LDS (wave wid owns s_csum[wid], s_vc[wid])
    if (lane < EE) {
        s_csum[wid][0][lane] = a0; s_csum[wid][1][lane] = a1;
        s_csum[wid][2][lane] = a2; s_csum[wid][3][lane] = a3;
        s_csum[wid][4][lane] = a4; s_csum[wid][5][lane] = a5;
        s_csum[wid][6][lane] = a6; s_csum[wid][7][lane] = a7;
    }
    if (lane == 0) {
        s_vc[wid][0] = (float)n0; s_vc[wid][1] = (float)n1;
        s_vc[wid][2] = (float)n2; s_vc[wid][3] = (float)n3;
        s_vc[wid][4] = (float)n4; s_vc[wid][5] = (float)n5;
        s_vc[wid][6] = (float)n6; s_vc[wid][7] = (float)n7;
    }
    __syncthreads();

    // ---------------- phase 2: long-term interest -> feat[128:176] ----------------
    if (tid < EE) {
        float acc = 0.f;
        #pragma unroll
        for (int g = 0; g < GG; g++) {
            int c = s_icode[g];
            acc += s_csum[g][c][tid] / fmaxf(s_vc[g][c], 1.0f);
        }
        s_feat[128 + tid] = acc * 0.25f;
    }

    // ---------------- phase 3: short-term attention ----------------
    float* Xs   = s_buf;                 // [64][PXE]
    float* wkq  = s_buf + SLEN * PXE;    // [48][8]
    float* bkq  = wkq + EE * NHH;        // [8]
    float* sc   = bkq + NHH;             // scores/attn [8][64]
    float* su   = sc + NHH * SLEN;       // [8][48]
    float* sctx = su + NHH * EE;         // [32]

    {
        int ids[3];
        #pragma unroll
        for (int i = 0; i < 3; i++) {
            int f = tid + 256 * i;
            int p = f / 12, q = f - 12 * p, fe = q >> 2;
            const int* idp = (fe == 0) ? st_g : (fe == 1) ? st_s : st_c;
            ids[i] = idp[b * SLEN + p];
        }
        float4 vs[3];
        #pragma unroll
        for (int i = 0; i < 3; i++) {
            int f = tid + 256 * i;
            int p = f / 12, q = f - 12 * p;
            vs[i] = ld4<BF16>(tbl, ids[i] * EMBD + ((q & 3) << 2));
        }
        #pragma unroll
        for (int i = 0; i < 3; i++) {
            int f = tid + 256 * i;
            int p = f / 12, q = f - 12 * p;
            *(float4*)&Xs[p * PXE + (q << 2)] = vs[i];
        }
    }
    if (tid < 64) {
        unsigned long long msk = __ballot(st_g[b * SLEN + tid] != 0);
        if (tid == 0) s_len = __popcll(msk);
    }
    for (int t = tid; t < EE * NHH; t += 256) {
        int e = t >> 3, h = t & 7;
        float acc = 0.f;
        #pragma unroll
        for (int d = 0; d < KDD; d++) acc += ldf<BF16>(wk, e * 32 + h * 4 + d) * s_q[h * 4 + d];
        wkq[t] = acc;
    }
    if (tid < NHH) {
        float acc = 0.f;
        #pragma unroll
        for (int d = 0; d < KDD; d++) acc += ldf<BF16>(bk, tid * 4 + d) * s_q[tid * 4 + d];
        bkq[tid] = acc;
    }
    __syncthreads();
    for (int t = tid; t < NHH * SLEN; t += 256) {
        int h = t >> 6, s = t & 63;
        float acc = bkq[h];
        for (int e = 0; e < EE; e++) acc += Xs[s * PXE + e] * wkq[e * NHH + h];
        acc *= 0.5f;
        if (s >= s_len) acc -= 1e9f;
        sc[h * SLEN + s] = acc;
    }
    __syncthreads();
    {
        for (int h = wid; h < NHH; h += 4) {
            float v = sc[h * SLEN + lane];
            float mx = v;
            #pragma unroll
            for (int o = 32; o; o >>= 1) mx = fmaxf(mx, __shfl_xor(mx, o));
            float ex = __expf(v - mx);
            float sm = ex;
            #pragma unroll
            for (int o = 32; o; o >>= 1) sm += __shfl_xor(sm, o);
            sc[h * SLEN + lane] = ex / sm;
        }
    }
    __syncthreads();
    for (int t = tid; t < NHH * EE; t += 256) {
        int h = t / EE, e = t - h * EE;
        float acc = 0.f;
        for (int s = 0; s < SLEN; s++) acc += sc[h * SLEN + s] * Xs[s * PXE + e];
        su[t] = acc;
    }
    __syncthreads();
    if (tid < 32) {
        float acc = ldf<BF16>(bv, tid);
        int h = tid >> 2;
        for (int e = 0; e < EE; e++) acc += su[h * EE + e] * ldf<BF16>(wv, e * 32 + tid);
        sctx[tid] = acc;
    }
    __syncthreads();
    if (tid < EE) {
        float acc = ldf<BF16>(bo, tid);
        #pragma unroll
        for (int i = 0; i < 32; i++) acc += sctx[i] * ldf<BF16>(wo, i * EE + tid);
        s_feat[176 + tid] = acc;
    }
    __syncthreads();

    // ---------------- phase 4: MLP 224 -> 200(LN,relu) -> 80(LN,relu) -> 1(sigmoid) ----------------
    float z1 = 0.f;
    if (tid < H1D) {
        z1 = ldf<BF16>(b1, tid);
        for (int i = 0; i < INDIM; i++) z1 += s_feat[i] * ldf<BF16>(w1, i * H1D + tid);
        s_buf[tid] = z1;
    }
    __syncthreads();
    if (tid < 64) {
        float sm = 0.f, sq = 0.f;
        for (int j = tid; j < H1D; j += 64) { float v = s_buf[j]; sm += v; sq += v * v; }
        #pragma unroll
        for (int o = 32; o; o >>= 1) { sm += __shfl_xor(sm, o); sq += __shfl_xor(sq, o); }
        if (tid == 0) { float mu = sm / H1D; s_mu = mu; s_rstd = rsqrtf(sq / H1D - mu * mu + 1e-3f); }
    }
    __syncthreads();
    if (tid < H1D) {
        float h = fmaxf(ldf<BF16>(g1, tid) * (z1 - s_mu) * s_rstd + ldf<BF16>(be1, tid), 0.f);
        s_buf[256 + tid] = h;
    }
    __syncthreads();
    float z2 = 0.f;
    if (tid < H2D) {
        z2 = ldf<BF16>(b2, tid);
        for (int i = 0; i < H1D; i++) z2 += s_buf[256 + i] * ldf<BF16>(w2, i * H2D + tid);
        s_buf[tid] = z2;
    }
    __syncthreads();
    if (tid < 64) {
        float sm = 0.f, sq = 0.f;
        for (int j = tid; j < H2D; j += 64) { float v = s_buf[j]; sm += v; sq += v * v; }
        #pragma unroll
        for (int o = 32; o; o >>= 1) { sm += __shfl_xor(sm, o); sq += __shfl_xor(sq, o); }
        if (tid == 0) { float mu = sm / H2D; s_mu = mu; s_rstd = rsqrtf(sq / H2D - mu * mu + 1e-3f); }
    }
    __syncthreads();
    if (tid < H2D) {
        float h = fmaxf(ldf<BF16>(g2, tid) * (z2 - s_mu) * s_rstd + ldf<BF16>(be2, tid), 0.f);
        s_red[tid] = h * ldf<BF16>(w3, tid);
    }
    __syncthreads();
    if (tid == 0) {
        float acc = ldf<BF16>(b3, 0);
        for (int i = 0; i < H2D; i++) acc += s_red[i];
        float sig = 1.f / (1.f + __expf(-acc));
        if constexpr (BF16) ((__hip_bfloat16*)outp)[b] = __float2bfloat16(sig);
        else                ((float*)outp)[b] = sig;
    }
}

extern "C" void kernel_launch(void* const* d_in, const int* in_sizes, int n_in,
                              void* d_out, int out_size, void* d_ws, size_t ws_size,
                              hipStream_t stream) {
    const int B = in_sizes[0];   // batch = 1024
    int*   flag = nullptr;
    float* hf   = nullptr;
    if (ws_size >= (16 + EE * 12) * sizeof(float)) {
        flag = (int*)d_ws;
        hf   = (float*)d_ws + 16;
        prep_kernel<<<1, 64, 0, stream>>>((const unsigned short*)d_in[14], d_in[15], flag, hf);
    }

#define ARGS \
        (const int*)d_in[0],  (const int*)d_in[1],  (const int*)d_in[2],              \
        (const int*)d_in[3],  (const int*)d_in[4],                                    \
        (const int*)d_in[5],  (const int*)d_in[6],  (const int*)d_in[7],              \
        (const int*)d_in[8],  (const int*)d_in[9],  (const int*)d_in[10],             \
        (const int*)d_in[11], (const int*)d_in[12], (const int*)d_in[13],             \
        (const void*)d_in[14], (const void*)d_in[15],                                 \
        (const void*)d_in[16], (const void*)d_in[17],                                 \
        (const void*)d_in[18], (const void*)d_in[19],                                 \
        (const void*)d_in[20], (const void*)d_in[21],                                 \
        (const void*)d_in[22], (const void*)d_in[23],                                 \
        (const void*)d_in[24], (const void*)d_in[25],                                 \
        (const void*)d_in[26], (const void*)d_in[27],                                 \
        (const void*)d_in[28], (const void*)d_in[29],                                 \
        (const void*)d_in[30], (const void*)d_in[31],                                 \
        (const void*)d_in[32], (const void*)d_in[33],                                 \
        d_out, flag, hf

    sdim_fwd<false><<<B, 256, 0, stream>>>(ARGS);
    sdim_fwd<true ><<<B, 256, 0, stream>>>(ARGS);
#undef ARGS
}

// Round 6
// 205.946 us; speedup vs baseline: 2.8812x; 1.4163x over previous
//
#include <hip/hip_runtime.h>
#include <hip/hip_bf16.h>

#define LLEN 512
#define SLEN 64
#define EMBD 16
#define EE 48
#define GG 4
#define NHH 8
#define KDD 4
#define INDIM 224
#define H1D 200
#define H2D 80
#define CHUNK 128
#define PXE 52   // row stride: 48 data + 4 selector floats

__device__ __forceinline__ float bf2f(unsigned short u) {
    union { unsigned int i; float f; } v; v.i = ((unsigned int)u) << 16; return v.f;
}

template<bool BF16>
__device__ __forceinline__ float ldf(const void* p, int i) {
    if constexpr (BF16) return bf2f(((const unsigned short*)p)[i]);
    else                return ((const float*)p)[i];
}

template<bool BF16>
__device__ __forceinline__ float4 ld4(const void* p, int i4) {
    if constexpr (BF16) {
        ushort4 u = ((const ushort4*)p)[i4 >> 2];
        return make_float4(bf2f(u.x), bf2f(u.y), bf2f(u.z), bf2f(u.w));
    } else {
        return ((const float4*)p)[i4 >> 2];
    }
}

struct Pool {
    float buf[CHUNK * PXE + 16];   // chunk rows (48 data + 4 sel) / attention / MLP scratch
    float part[GG][GG][EE];        // [wid][g][e] partial selected-bucket sums
    float hf[12 * EE];             // H transposed fp32: hf[j*48+e] = H[e][j]
    float feat[INDIM];
    float q[NHH * KDD];
    float red[128];
    int   pc[2][GG];               // counts from waves 0,2
    int   icode[GG];
    int   len;
    float mu, rstd;
};

template<bool BF16>
__device__ void sdim_body(Pool& P,
    const int* uid, const int* ut1, const int* ut2, const int* ut3, const int* ut4,
    const int* lb_g, const int* lb_s, const int* lb_c,
    const int* lt_g, const int* lt_s, const int* lt_c,
    const int* st_g, const int* st_s, const int* st_c,
    const void* tbl, const void* Hm,
    const void* wq, const void* bq, const void* wk, const void* bk,
    const void* wvv, const void* bv, const void* wo, const void* bo,
    const void* w1, const void* b1, const void* g1, const void* be1,
    const void* w2, const void* b2, const void* g2, const void* be2,
    const void* w3, const void* b3, void* outp)
{
    const int b = blockIdx.x;
    const int tid = threadIdx.x;
    const int lane = tid & 63;
    const int wid = __builtin_amdgcn_readfirstlane(tid >> 6);   // 0..3 uniform

    // ---------------- phase 0: H -> fp32 transposed LDS; Xu/Xi embeds ----------------
    for (int i = tid; i < 12 * EE; i += 256) {
        int j = i / EE, e = i - j * EE;
        P.hf[i] = ldf<BF16>(Hm, e * 12 + j);
    }
    if (tid < 80) {
        int f = tid >> 4, e = tid & 15;
        int id = (f == 0) ? uid[b] : (f == 1) ? ut1[b] : (f == 2) ? ut2[b] : (f == 3) ? ut3[b] : ut4[b];
        P.feat[tid] = ldf<BF16>(tbl, id * EMBD + e);
    } else if (tid < 128) {
        int t = tid - 80; int f = t >> 4, e = t & 15;
        int id = (f == 0) ? lb_g[b] : (f == 1) ? lb_s[b] : lb_c[b];
        P.feat[80 + t] = ldf<BF16>(tbl, id * EMBD + e);
    }
    __syncthreads();

    // ---------------- phase 0.5: q projection + item LSH codes ----------------
    if (tid < 32) {
        float acc = ldf<BF16>(bq, tid);
        for (int e = 0; e < EE; e++) acc += P.feat[80 + e] * ldf<BF16>(wq, e * 32 + tid);
        P.q[tid] = acc;
    }
    if (tid >= 64 && tid < 76) {
        int j = tid - 64;
        float acc = 0.f;
        for (int e = 0; e < EE; e++) acc += P.feat[80 + e] * P.hf[j * EE + e];
        P.red[j] = acc;
    }
    __syncthreads();
    if (tid < GG) {
        int code = 0;
        #pragma unroll
        for (int m = 0; m < 3; m++) if (P.red[tid * 3 + m] > 0.f) code |= (1 << m);
        P.icode[tid] = code;
    }

    // ---------------- phase 1: long-term, 4 chunks of 128 positions ----------------
    float accg[GG] = {0.f, 0.f, 0.f, 0.f};     // per-wave selected-bucket sums (lane = e)
    int   cnt[GG]  = {0, 0, 0, 0};             // wave-uniform counts (waves 0,2)
    const int offs = (lane < 52) ? lane : 51;  // lanes 0..47: data; 48..51: selectors

    for (int ch = 0; ch < LLEN / CHUNK; ch++) {
        const int base = ch * CHUNK;
        // A: pipelined gather: ids -> gathers -> LDS stores
        {
            int ids[6];
            #pragma unroll
            for (int i = 0; i < 6; i++) {
                int f = tid + 256 * i;
                int p = f / 12, qq = f - 12 * p, fe = qq >> 2;
                const int* idp = (fe == 0) ? lt_g : (fe == 1) ? lt_s : lt_c;
                ids[i] = idp[b * LLEN + base + p];
            }
            float4 vs[6];
            #pragma unroll
            for (int i = 0; i < 6; i++) {
                int f = tid + 256 * i;
                int p = f / 12, qq = f - 12 * p;
                vs[i] = ld4<BF16>(tbl, ids[i] * EMBD + ((qq & 3) << 2));
            }
            #pragma unroll
            for (int i = 0; i < 6; i++) {
                int f = tid + 256 * i;
                int p = f / 12, qq = f - 12 * p;
                *(float4*)&P.buf[p * PXE + (qq << 2)] = vs[i];
            }
        }
        __syncthreads();
        // B: LSH codes + selector floats, one thread per position (waves 0,2)
        if (!(wid & 1)) {
            const int p = ((wid >> 1) << 6) | lane;
            const float* row = &P.buf[p * PXE];
            float4 x[12];
            #pragma unroll
            for (int k = 0; k < 12; k++) x[k] = *(const float4*)(row + 4 * k);
            float acc[12];
            #pragma unroll
            for (int j = 0; j < 12; j++) {
                const float4* hr = (const float4*)&P.hf[j * EE];
                float s = 0.f;
                #pragma unroll
                for (int k = 0; k < 12; k++) {
                    float4 h4 = hr[k];
                    s += x[k].x * h4.x + x[k].y * h4.y + x[k].z * h4.z + x[k].w * h4.w;
                }
                acc[j] = s;
            }
            int code[GG];
            #pragma unroll
            for (int g = 0; g < GG; g++) {
                int c = 0;
                #pragma unroll
                for (int m = 0; m < 3; m++) if (acc[g * 3 + m] > 0.f) c |= (1 << m);
                code[g] = c;
            }
            int valid = (lt_g[b * LLEN + base + p] != 0);
            float4 sel;
            sel.x = (code[0] == P.icode[0] && valid) ? 1.f : 0.f;
            sel.y = (code[1] == P.icode[1] && valid) ? 1.f : 0.f;
            sel.z = (code[2] == P.icode[2] && valid) ? 1.f : 0.f;
            sel.w = (code[3] == P.icode[3] && valid) ? 1.f : 0.f;
            *(float4*)&P.buf[p * PXE + 48] = sel;
            // counts include padded positions (ref one-hot semantics)
            #pragma unroll
            for (int g = 0; g < GG; g++)
                cnt[g] += __popcll(__ballot(code[g] == P.icode[g]));
        }
        __syncthreads();
        // C: selected-bucket accumulation — branch-free, scalar-free.
        // Wave wid covers positions wid*32..wid*32+31; one ds_read fetches row data
        // (lanes 0..47) AND the 4 selectors (lanes 48..51); readlane broadcasts sel.
        {
            const float* basep = &P.buf[(wid * 32) * PXE] + offs;
            #pragma unroll
            for (int i = 0; i < 32; i++) {
                float xv = basep[i * PXE];
                #pragma unroll
                for (int g = 0; g < GG; g++) {
                    float sel = __int_as_float(
                        __builtin_amdgcn_readlane(__float_as_int(xv), 48 + g));
                    accg[g] += sel * xv;
                }
            }
        }
        __syncthreads();
    }
    // flush partials + counts
    if (lane < EE) {
        #pragma unroll
        for (int g = 0; g < GG; g++) P.part[wid][g][lane] = accg[g];
    }
    if (!(wid & 1) && lane == 0) {
        #pragma unroll
        for (int g = 0; g < GG; g++) P.pc[wid >> 1][g] = cnt[g];
    }
    __syncthreads();

    // ---------------- phase 2: long-term interest -> feat[128:176] ----------------
    if (tid < EE) {
        float r = 0.f;
        #pragma unroll
        for (int g = 0; g < GG; g++) {
            float c = (float)(P.pc[0][g] + P.pc[1][g]);
            float s = P.part[0][g][tid] + P.part[1][g][tid] + P.part[2][g][tid] + P.part[3][g][tid];
            r += s / fmaxf(c, 1.0f);   // c==0 => s==0 => 0 (matches ref where())
        }
        P.feat[128 + tid] = r * 0.25f;
    }

    // ---------------- phase 3: short-term attention ----------------
    float* Xs   = P.buf;                 // [64][PXE]
    float* wkq  = P.buf + SLEN * PXE;    // [48][8]
    float* bkq  = wkq + EE * NHH;        // [8]
    float* sc   = bkq + NHH;             // scores/attn [8][64]
    float* su   = sc + NHH * SLEN;       // [8][48]
    float* sctx = su + NHH * EE;         // [32]

    {
        int ids[3];
        #pragma unroll
        for (int i = 0; i < 3; i++) {
            int f = tid + 256 * i;
            int p = f / 12, qq = f - 12 * p, fe = qq >> 2;
            const int* idp = (fe == 0) ? st_g : (fe == 1) ? st_s : st_c;
            ids[i] = idp[b * SLEN + p];
        }
        float4 vs[3];
        #pragma unroll
        for (int i = 0; i < 3; i++) {
            int f = tid + 256 * i;
            int p = f / 12, qq = f - 12 * p;
            vs[i] = ld4<BF16>(tbl, ids[i] * EMBD + ((qq & 3) << 2));
        }
        #pragma unroll
        for (int i = 0; i < 3; i++) {
            int f = tid + 256 * i;
            int p = f / 12, qq = f - 12 * p;
            *(float4*)&Xs[p * PXE + (qq << 2)] = vs[i];
        }
    }
    if (tid < 64) {
        unsigned long long msk = __ballot(st_g[b * SLEN + tid] != 0);
        if (tid == 0) P.len = __popcll(msk);
    }
    for (int t = tid; t < EE * NHH; t += 256) {
        int e = t >> 3, h = t & 7;
        float acc = 0.f;
        #pragma unroll
        for (int d = 0; d < KDD; d++) acc += ldf<BF16>(wk, e * 32 + h * 4 + d) * P.q[h * 4 + d];
        wkq[t] = acc;
    }
    if (tid < NHH) {
        float acc = 0.f;
        #pragma unroll
        for (int d = 0; d < KDD; d++) acc += ldf<BF16>(bk, tid * 4 + d) * P.q[tid * 4 + d];
        bkq[tid] = acc;
    }
    __syncthreads();
    for (int t = tid; t < NHH * SLEN; t += 256) {
        int h = t >> 6, s = t & 63;
        float acc = bkq[h];
        for (int e = 0; e < EE; e++) acc += Xs[s * PXE + e] * wkq[e * NHH + h];
        acc *= 0.5f;
        if (s >= P.len) acc -= 1e9f;
        sc[h * SLEN + s] = acc;
    }
    __syncthreads();
    for (int h = wid; h < NHH; h += 4) {
        float v = sc[h * SLEN + lane];
        float mx = v;
        #pragma unroll
        for (int o = 32; o; o >>= 1) mx = fmaxf(mx, __shfl_xor(mx, o));
        float ex = __expf(v - mx);
        float sm = ex;
        #pragma unroll
        for (int o = 32; o; o >>= 1) sm += __shfl_xor(sm, o);
        sc[h * SLEN + lane] = ex / sm;
    }
    __syncthreads();
    for (int t = tid; t < NHH * EE; t += 256) {
        int h = t / EE, e = t - h * EE;
        float acc = 0.f;
        for (int s = 0; s < SLEN; s++) acc += sc[h * SLEN + s] * Xs[s * PXE + e];
        su[t] = acc;
    }
    __syncthreads();
    if (tid < 32) {
        float acc = ldf<BF16>(bv, tid);
        int h = tid >> 2;
        for (int e = 0; e < EE; e++) acc += su[h * EE + e] * ldf<BF16>(wvv, e * 32 + tid);
        sctx[tid] = acc;
    }
    __syncthreads();
    if (tid < EE) {
        float acc = ldf<BF16>(bo, tid);
        #pragma unroll
        for (int i = 0; i < 32; i++) acc += sctx[i] * ldf<BF16>(wo, i * EE + tid);
        P.feat[176 + tid] = acc;
    }
    __syncthreads();

    // ---------------- phase 4: MLP 224 -> 200(LN,relu) -> 80(LN,relu) -> 1(sigmoid) ----------------
    float z1 = 0.f;
    if (tid < H1D) {
        z1 = ldf<BF16>(b1, tid);
        for (int i = 0; i < INDIM; i++) z1 += P.feat[i] * ldf<BF16>(w1, i * H1D + tid);
        P.buf[tid] = z1;
    }
    __syncthreads();
    if (tid < 64) {
        float sm = 0.f, sq = 0.f;
        for (int j = tid; j < H1D; j += 64) { float v = P.buf[j]; sm += v; sq += v * v; }
        #pragma unroll
        for (int o = 32; o; o >>= 1) { sm += __shfl_xor(sm, o); sq += __shfl_xor(sq, o); }
        if (tid == 0) { float mu = sm / H1D; P.mu = mu; P.rstd = rsqrtf(sq / H1D - mu * mu + 1e-3f); }
    }
    __syncthreads();
    if (tid < H1D) {
        float h = fmaxf(ldf<BF16>(g1, tid) * (z1 - P.mu) * P.rstd + ldf<BF16>(be1, tid), 0.f);
        P.buf[256 + tid] = h;
    }
    __syncthreads();
    float z2 = 0.f;
    if (tid < H2D) {
        z2 = ldf<BF16>(b2, tid);
        for (int i = 0; i < H1D; i++) z2 += P.buf[256 + i] * ldf<BF16>(w2, i * H2D + tid);
        P.buf[tid] = z2;
    }
    __syncthreads();
    if (tid < 64) {
        float sm = 0.f, sq = 0.f;
        for (int j = tid; j < H2D; j += 64) { float v = P.buf[j]; sm += v; sq += v * v; }
        #pragma unroll
        for (int o = 32; o; o >>= 1) { sm += __shfl_xor(sm, o); sq += __shfl_xor(sq, o); }
        if (tid == 0) { float mu = sm / H2D; P.mu = mu; P.rstd = rsqrtf(sq / H2D - mu * mu + 1e-3f); }
    }
    __syncthreads();
    if (tid < H2D) {
        float h = fmaxf(ldf<BF16>(g2, tid) * (z2 - P.mu) * P.rstd + ldf<BF16>(be2, tid), 0.f);
        P.red[tid] = h * ldf<BF16>(w3, tid);
    }
    __syncthreads();
    if (tid == 0) {
        float acc = ldf<BF16>(b3, 0);
        for (int i = 0; i < H2D; i++) acc += P.red[i];
        float sig = 1.f / (1.f + __expf(-acc));
        if constexpr (BF16) ((__hip_bfloat16*)outp)[b] = __float2bfloat16(sig);
        else                ((float*)outp)[b] = sig;
    }
}

__global__ __launch_bounds__(256, 4) void sdim_fwd(
    const int* __restrict__ uid, const int* __restrict__ ut1, const int* __restrict__ ut2,
    const int* __restrict__ ut3, const int* __restrict__ ut4,
    const int* __restrict__ lb_g, const int* __restrict__ lb_s, const int* __restrict__ lb_c,
    const int* __restrict__ lt_g, const int* __restrict__ lt_s, const int* __restrict__ lt_c,
    const int* __restrict__ st_g, const int* __restrict__ st_s, const int* __restrict__ st_c,
    const void* __restrict__ tbl, const void* __restrict__ Hm,
    const void* __restrict__ wq, const void* __restrict__ bq,
    const void* __restrict__ wk, const void* __restrict__ bk,
    const void* __restrict__ wvv, const void* __restrict__ bv,
    const void* __restrict__ wo, const void* __restrict__ bo,
    const void* __restrict__ w1, const void* __restrict__ b1,
    const void* __restrict__ g1, const void* __restrict__ be1,
    const void* __restrict__ w2, const void* __restrict__ b2,
    const void* __restrict__ g2, const void* __restrict__ be2,
    const void* __restrict__ w3, const void* __restrict__ b3,
    void* __restrict__ outp)
{
    __shared__ Pool P;
    __shared__ int s_isbf;
    // in-block dtype detection: even ushort indices of bf16 data are small values
    // (exp<127); of fp32 they are random mantissa bits (P[all 128 exp<127] ~ 2^-128)
    if (threadIdx.x < 64) {
        int big = 0;
        for (int i = (threadIdx.x & 63); i < 128; i += 64) {
            unsigned short u = ((const unsigned short*)tbl)[2 * i];
            if (((u >> 7) & 0xFF) >= 127) big = 1;
        }
        unsigned long long m = __ballot(big);
        if (threadIdx.x == 0) s_isbf = (m == 0ull) ? 1 : 0;
    }
    __syncthreads();
    if (s_isbf)
        sdim_body<true >(P, uid, ut1, ut2, ut3, ut4, lb_g, lb_s, lb_c, lt_g, lt_s, lt_c,
                         st_g, st_s, st_c, tbl, Hm, wq, bq, wk, bk, wvv, bv, wo, bo,
                         w1, b1, g1, be1, w2, b2, g2, be2, w3, b3, outp);
    else
        sdim_body<false>(P, uid, ut1, ut2, ut3, ut4, lb_g, lb_s, lb_c, lt_g, lt_s, lt_c,
                         st_g, st_s, st_c, tbl, Hm, wq, bq, wk, bk, wvv, bv, wo, bo,
                         w1, b1, g1, be1, w2, b2, g2, be2, w3, b3, outp);
}

extern "C" void kernel_launch(void* const* d_in, const int* in_sizes, int n_in,
                              void* d_out, int out_size, void* d_ws, size_t ws_size,
                              hipStream_t stream) {
    const int B = in_sizes[0];   // batch = 1024
    sdim_fwd<<<B, 256, 0, stream>>>(
        (const int*)d_in[0],  (const int*)d_in[1],  (const int*)d_in[2],
        (const int*)d_in[3],  (const int*)d_in[4],
        (const int*)d_in[5],  (const int*)d_in[6],  (const int*)d_in[7],
        (const int*)d_in[8],  (const int*)d_in[9],  (const int*)d_in[10],
        (const int*)d_in[11], (const int*)d_in[12], (const int*)d_in[13],
        (const void*)d_in[14], (const void*)d_in[15],
        (const void*)d_in[16], (const void*)d_in[17],
        (const void*)d_in[18], (const void*)d_in[19],
        (const void*)d_in[20], (const void*)d_in[21],
        (const void*)d_in[22], (const void*)d_in[23],
        (const void*)d_in[24], (const void*)d_in[25],
        (const void*)d_in[26], (const void*)d_in[27],
        (const void*)d_in[28], (const void*)d_in[29],
        (const void*)d_in[30], (const void*)d_in[31],
        (const void*)d_in[32], (const void*)d_in[33],
        d_out);
}